// Round 2
// baseline (203.765 us; speedup 1.0000x reference)
//
#include <hip/hip_runtime.h>
#include <hip/hip_bf16.h>
#include <stdint.h>

#define BDIM 2048
#define HDIM 1024
#define XDIM 1024
#define BH (BDIM*HDIM)
#define WSEG 1048576  // 1M elements per segment

typedef __attribute__((ext_vector_type(8))) short short8;
typedef __attribute__((ext_vector_type(4))) float float4v;

__device__ __forceinline__ void gload16(const void* g, void* l) {
    __builtin_amdgcn_global_load_lds(
        (const __attribute__((address_space(1))) unsigned int*)g,
        (__attribute__((address_space(3))) unsigned int*)l, 16, 0, 0);
}

__device__ __forceinline__ unsigned pack2(float a, float b) {
    __hip_bfloat162 v = __float22bfloat162_rn(make_float2(a, b));
    return *reinterpret_cast<unsigned*>(&v);
}
__device__ __forceinline__ uint2 pack4(float4 f) {
    return make_uint2(pack2(f.x, f.y), pack2(f.z, f.w));
}
__device__ __forceinline__ float2 up2(unsigned u) {
    __hip_bfloat162 v = *reinterpret_cast<__hip_bfloat162*>(&u);
    return __bfloat1622float2(v);
}

// ---------------- prep_all: fp32 -> bf16 for everything the GEMM eats ----------------
// ws bf16 segment map (1M elems each):
//   segs 0..7  : wxi,wxf,wxc,wxo,whi,whf,whc,who
//   segs 8..9  : x (rows 0..1023, 1024..2047)
//   segs 10..17: hm[g][rowhalf] = h0 * maskHg   (hm_g contiguous as 2048x1024)
__global__ __launch_bounds__(256) void prep_all_k(
    const float* __restrict__ w0, const float* __restrict__ w1,
    const float* __restrict__ w2, const float* __restrict__ w3,
    const float* __restrict__ w4, const float* __restrict__ w5,
    const float* __restrict__ w6, const float* __restrict__ w7,
    const float* __restrict__ x, const float* __restrict__ h0,
    const float* __restrict__ mI, const float* __restrict__ mF,
    const float* __restrict__ mC, const float* __restrict__ mO,
    uint2* __restrict__ dst) {
    const int seg = blockIdx.y;
    const int i = blockIdx.x * 256 + threadIdx.x;   // float4 index within segment (262144)
    float4 f;
    if (seg < 10) {
        const float* base;
        switch (seg) {
            case 0: base = w0; break; case 1: base = w1; break;
            case 2: base = w2; break; case 3: base = w3; break;
            case 4: base = w4; break; case 5: base = w5; break;
            case 6: base = w6; break; case 7: base = w7; break;
            default: base = x + (size_t)(seg - 8) * WSEG; break;
        }
        f = ((const float4*)base)[i];
    } else {
        const int s = seg - 10;
        const int g = s >> 1, half = s & 1;
        const float* mp = (g == 0) ? mI : (g == 1) ? mF : (g == 2) ? mC : mO;
        float4 h = ((const float4*)(h0 + (size_t)half * WSEG))[i];
        float4 m = ((const float4*)(mp + (size_t)half * WSEG))[i];
        f = make_float4(h.x * m.x, h.y * m.y, h.z * m.z, h.w * m.w);
    }
    dst[(size_t)seg * (WSEG / 4) + i] = pack4(f);
}

// ---------------- gemm split-K, 256x256 tile, 1-barrier-per-K-tile schedule ----------------
// part[z=2g+half][b][n] = A_half[b,:]·B_gh[n,:]  (bf16 out), K=1024 per block.
// Grid 256 = 8 z (id&7 -> one z per XCD) x 4 by x 8 bx; 512 threads = 8 waves (2M x 4N),
// per-wave output 128x64 via 8x4 of 16x16x32 bf16 MFMA per BK=64 K-tile, 16 tiles.
// LDS 128 KiB: A double-buffered 2x(256x64), B same.  Per tile k:
//   stage(k+1): 8 global_load_lds_dwordx4/thread into buffer (k+1)&1   (issued FIRST)
//   compute(k): 24 ds_read_b128 + 64 MFMA from buffer k&1, compiler-scheduled (no
//               intra-tile barriers -- buffer is read-only for the whole tile, staging
//               targets the other buffer, so read latency overlaps MFMA freely)
//   s_waitcnt vmcnt(0)  -- drains stage(k+1), issued ~600cy earlier -> nearly free
//   s_barrier           -- tile boundary: WAR (all waves done reading ~P before k+2
//                          staging overwrites it) + RAW (k+1's loads visible to all)
// This removes R1's 16-barriers/iter lockstep whose per-phase lgkm stall capped
// MfmaUtil at 32%.  LDS XOR swizzle unchanged (pre-swizzled global src, conflicts=0).

#define BARRIER() asm volatile("s_barrier" ::: "memory")

__global__ __launch_bounds__(512, 2) void gemm_split(
    const __hip_bfloat16* __restrict__ ws18,  // 18 x 1M bf16 per prep_all map
    __hip_bfloat16* __restrict__ part) {      // 8 x BH bf16
    const int id = blockIdx.x;
    const int z = id & 7;
    const int w = id >> 3;
    const int by = w & 3;
    const int bx = w >> 2;
    const int g = z >> 1, half = z & 1;
    const __hip_bfloat16* Ap = half ? (ws18 + (size_t)(10 + 2 * g) * WSEG)
                                    : (ws18 + (size_t)8 * WSEG);
    const __hip_bfloat16* Bp = half ? (ws18 + (size_t)(4 + g) * WSEG)
                                    : (ws18 + (size_t)g * WSEG);

    __shared__ short lds[65536];   // 128 KiB: A buf0 @0B, A buf1 @32768B, B bufs @65536B+

    const int t = threadIdx.x;
    const int m0 = bx * 256, n0 = by * 256;
    const int wid = t >> 6, lane = t & 63;
    const int wm_i = wid >> 2, wn_i = wid & 3;   // 2 x 4 wave grid
    const int lrow = lane & 15, quad = lane >> 4;
    const short8* L8 = (const short8*)lds;

    float4v acc[8][4];
#pragma unroll
    for (int i = 0; i < 8; ++i)
#pragma unroll
        for (int j = 0; j < 4; ++j) acc[i][j] = (float4v){0.f, 0.f, 0.f, 0.f};

    // stage K-tile k: A/B 256 rows x 64 cols bf16 each = 2048 chunks of 16B per matrix,
    // 512 threads x 4 chunks.  chunk c -> row = c>>3, SRC col-group = (c&7)^(row&7)
    // (global-side swizzle; LDS dest linear as required by global_load_lds).
    auto stage = [&](int k) {
        const int bufB = (k & 1) * 32768;   // byte offset of buffer
        const int kc = k * 64;
#pragma unroll
        for (int it = 0; it < 4; ++it) {
            const int c = it * 512 + t;
            const int row = c >> 3;
            const int cg = (c & 7) ^ (row & 7);
            gload16(Ap + (size_t)(m0 + row) * 1024 + kc + cg * 8,
                    (char*)lds + bufB + c * 16);
            gload16(Bp + (size_t)(n0 + row) * 1024 + kc + cg * 8,
                    (char*)lds + 65536 + bufB + c * 16);
        }
    };

    // compute K-tile k from buffer k&1: logical col-chunk q of row r lives at
    // short8 index base + r*8 + (q^(r&7))
    auto compute = [&](int k) {
        const int ab = (k & 1) * 2048;      // short8 index of A buffer
        const int bb = 4096 + ab;           // short8 index of B buffer
        short8 bfr[4][2];
#pragma unroll
        for (int nt = 0; nt < 4; ++nt) {
            const int rb = wn_i * 64 + nt * 16 + lrow;
#pragma unroll
            for (int ks = 0; ks < 2; ++ks)
                bfr[nt][ks] = L8[bb + (rb << 3) + ((ks * 4 + quad) ^ (rb & 7))];
        }
#pragma unroll
        for (int mt = 0; mt < 8; ++mt) {
            const int ra = wm_i * 128 + mt * 16 + lrow;
            short8 a0 = L8[ab + (ra << 3) + (quad ^ (ra & 7))];
            short8 a1 = L8[ab + (ra << 3) + ((4 + quad) ^ (ra & 7))];
#pragma unroll
            for (int nt = 0; nt < 4; ++nt) {
                acc[mt][nt] = __builtin_amdgcn_mfma_f32_16x16x32_bf16(
                    a0, bfr[nt][0], acc[mt][nt], 0, 0, 0);
                acc[mt][nt] = __builtin_amdgcn_mfma_f32_16x16x32_bf16(
                    a1, bfr[nt][1], acc[mt][nt], 0, 0, 0);
            }
        }
    };

    // prologue: tile 0 staged and drained once (cold-latency hit taken once per block)
    stage(0);
    asm volatile("s_waitcnt vmcnt(0)" ::: "memory");
    BARRIER();

#pragma unroll 1
    for (int k = 0; k < 16; ++k) {
        if (k < 15) stage(k + 1);   // issue early: drains at tile end, ~free
        compute(k);
        asm volatile("s_waitcnt vmcnt(0)" ::: "memory");
        BARRIER();
    }

    // epilogue: C/D layout col=lane&15, row=quad*4+r (m89/m91 verified); bf16 partial
    __hip_bfloat16* pz = part + (size_t)z * BH;
#pragma unroll
    for (int mt = 0; mt < 8; ++mt) {
        const int rowb = m0 + wm_i * 128 + mt * 16 + quad * 4;
#pragma unroll
        for (int nt = 0; nt < 4; ++nt) {
            const int col = n0 + wn_i * 64 + nt * 16 + lrow;
#pragma unroll
            for (int r = 0; r < 4; ++r)
                pz[(size_t)(rowb + r) * HDIM + col] = __float2bfloat16(acc[mt][nt][r]);
        }
    }
}

// ---------------- combine: sum split-K partials + bias -> gates -> h1, c1 (fp32 out) ----------------
__global__ __launch_bounds__(256) void combine_k(
    const uint2* __restrict__ part,   // 8 x BH bf16, as uint2 = 4 elems
    const float* __restrict__ bi, const float* __restrict__ bff,
    const float* __restrict__ bc, const float* __restrict__ bo,
    const float* __restrict__ c0, const float* __restrict__ mC,
    float4* __restrict__ out) {
    const int i = blockIdx.x * 256 + threadIdx.x;   // 4-elem group index over BH/4
    const int h4 = (i * 4 & (HDIM - 1)) >> 2;       // float4 index into biases

    float gate[4][4];
#pragma unroll
    for (int g = 0; g < 4; ++g) {
        uint2 p0 = part[(size_t)(2 * g) * (BH / 4) + i];
        uint2 p1 = part[(size_t)(2 * g + 1) * (BH / 4) + i];
        float2 a0 = up2(p0.x), a1 = up2(p0.y);
        float2 b0 = up2(p1.x), b1 = up2(p1.y);
        gate[g][0] = a0.x + b0.x;
        gate[g][1] = a0.y + b0.y;
        gate[g][2] = a1.x + b1.x;
        gate[g][3] = a1.y + b1.y;
    }
    float4 vbi = ((const float4*)bi)[h4];
    float4 vbf = ((const float4*)bff)[h4];
    float4 vbc = ((const float4*)bc)[h4];
    float4 vbo = ((const float4*)bo)[h4];
    float4 vc0 = ((const float4*)c0)[i];
    float4 vmc = ((const float4*)mC)[i];
    const float* pbi = (const float*)&vbi;
    const float* pbf = (const float*)&vbf;
    const float* pbc = (const float*)&vbc;
    const float* pbo = (const float*)&vbo;
    const float* pc0 = (const float*)&vc0;
    const float* pmc = (const float*)&vmc;

    float h1[4], c1[4];
#pragma unroll
    for (int j = 0; j < 4; ++j) {
        float xi = gate[0][j] + pbi[j];
        float xf = gate[1][j] + pbf[j];
        float xc = gate[2][j] + pbc[j];
        float xo = gate[3][j] + pbo[j];
        float I = 1.f / (1.f + __expf(-xi));
        float F = 1.f / (1.f + __expf(-xf));
        float C = tanhf(xc) * pmc[j];
        float O = 1.f / (1.f + __expf(-xo));
        c1[j] = F * pc0[j] + I * C;
        h1[j] = O * tanhf(c1[j]);
    }
    out[i] = make_float4(h1[0], h1[1], h1[2], h1[3]);
    out[BH / 4 + i] = make_float4(c1[0], c1[1], c1[2], c1[3]);
}

extern "C" void kernel_launch(void* const* d_in, const int* in_sizes, int n_in,
                              void* d_out, int out_size, void* d_ws, size_t ws_size,
                              hipStream_t stream) {
    const float* x   = (const float*)d_in[0];
    const float* h0  = (const float*)d_in[1];
    const float* c0  = (const float*)d_in[2];
    const float* wxi = (const float*)d_in[3];
    const float* wxf = (const float*)d_in[4];
    const float* wxc = (const float*)d_in[5];
    const float* wxo = (const float*)d_in[6];
    const float* whi = (const float*)d_in[7];
    const float* whf = (const float*)d_in[8];
    const float* whc = (const float*)d_in[9];
    const float* who = (const float*)d_in[10];
    const float* bi  = (const float*)d_in[11];
    const float* bf  = (const float*)d_in[12];
    const float* bc  = (const float*)d_in[13];
    const float* bo  = (const float*)d_in[14];
    const float* mI  = (const float*)d_in[15];
    const float* mF  = (const float*)d_in[16];
    const float* mC  = (const float*)d_in[17];
    const float* mO  = (const float*)d_in[18];
    const float* mCell = (const float*)d_in[19];

    // ws layout: 18*1M bf16 = 36 MB | part: 8*BH bf16 = 32 MB
    __hip_bfloat16* ws18 = (__hip_bfloat16*)d_ws;
    __hip_bfloat16* part = ws18 + (size_t)18 * WSEG;

    prep_all_k<<<dim3(WSEG / 4 / 256, 18), dim3(256), 0, stream>>>(
        wxi, wxf, wxc, wxo, whi, whf, whc, who, x, h0, mI, mF, mC, mO,
        (uint2*)ws18);

    gemm_split<<<dim3(256), dim3(512), 0, stream>>>(ws18, part);

    combine_k<<<dim3(BH / 4 / 256), dim3(256), 0, stream>>>(
        (const uint2*)part, bi, bf, bc, bo, c0, mCell, (float4*)d_out);
}